// Round 1
// baseline (7623.151 us; speedup 1.0000x reference)
//
#include <hip/hip_runtime.h>

// RNNModule: LSTM-like scan with shared gate pre-activation.
// B=128, L=256, D=512, H=1024, O=2.
//
// Pipeline (all on `stream`):
//  k0_prep : transpose+convert Wh->Whb_t[n][k] bf16, Wx->Wxb_t[n][k] bf16,
//            bxh = bx+bh, zero group barriers.
//  k1_xproj: xpT[l][n][b] = bf16( x[b,l,:]@Wx[:,n] + bx[n] + bh[n] )  (MFMA bf16)
//  k2_scan : 256 sequential steps. 8 independent groups (16 batch rows each),
//            32 WGs/group (32 cols each, 2 waves x 16 cols). Wh column slice
//            lives in VGPRs for the whole scan. Per-group atomic barrier
//            (agent scope) between steps. h history stored bf16 in hs[l][b][n].
//  k3_out  : out[b*L+l] = mask ? sigmoid(hs[l][b]@Wo + bo) : (0,1)

#define B_ 128
#define L_ 256
#define D_ 512
#define H_ 1024

typedef __attribute__((ext_vector_type(8))) short short8;
typedef __attribute__((ext_vector_type(4))) float f32x4;
typedef __attribute__((ext_vector_type(2))) float f32x2;
typedef __attribute__((ext_vector_type(4))) unsigned short u16x4;

__device__ __forceinline__ unsigned short f2bf(float f) {
    unsigned int u = __float_as_uint(f);
    return (unsigned short)((u + 0x8000u) >> 16);  // round-half-up to bf16
}
__device__ __forceinline__ float bf2f(unsigned short s) {
    return __uint_as_float(((unsigned int)s) << 16);
}

// ---------------------------------------------------------------- k0: prep
__global__ __launch_bounds__(256) void k0_prep(
    const float* __restrict__ Wh, const float* __restrict__ Wx,
    const float* __restrict__ bh, const float* __restrict__ bx,
    unsigned short* __restrict__ Whb_t, unsigned short* __restrict__ Wxb_t,
    float* __restrict__ bxh, int* __restrict__ bar)
{
    const int stride = gridDim.x * blockDim.x;
    const int t0 = blockIdx.x * blockDim.x + threadIdx.x;
    // Whb_t[n][k] = bf16(Wh[k][n]); coalesced writes, strided reads (one-time)
    for (int i = t0; i < H_ * H_; i += stride) {
        int n = i >> 10, k = i & 1023;
        Whb_t[i] = f2bf(Wh[k * H_ + n]);
    }
    // Wxb_t[n][k] = bf16(Wx[k][n])
    for (int i = t0; i < H_ * D_; i += stride) {
        int n = i >> 9, k = i & 511;
        Wxb_t[i] = f2bf(Wx[k * H_ + n]);
    }
    for (int i = t0; i < H_; i += stride) bxh[i] = bx[i] + bh[i];
    for (int i = t0; i < 256; i += stride) bar[i] = 0;
}

// ------------------------------------------------------------ k1: x @ Wx
// Grid: 2048 WGs x 256 thr. WG: 64 rows (m = l*128+b) x 256 cols.
// Wave w: rows m0+16w..+15, all 256 cols (16 N-tiles of 16).
__global__ __launch_bounds__(256) void k1_xproj(
    const float* __restrict__ x, const unsigned short* __restrict__ Wxb_t,
    const float* __restrict__ bxh, unsigned short* __restrict__ xpT)
{
    const int nt   = blockIdx.x & 3;
    const int mt   = blockIdx.x >> 2;
    const int w    = threadIdx.x >> 6;
    const int lane = threadIdx.x & 63;
    const int m    = lane & 15, q = lane >> 4;
    const int m0   = mt * 64;
    const int l    = m0 >> 7;            // 64 | m0, so whole WG shares l
    const int brow = (m0 & 127) + w * 16;
    const int n0   = nt * 256;

    const float* ap = x + ((size_t)(brow + m) * L_ + l) * D_ + q * 8;

    f32x4 acc[16];
#pragma unroll
    for (int t = 0; t < 16; ++t) acc[t] = (f32x4){0.f, 0.f, 0.f, 0.f};

#pragma unroll 4
    for (int kk = 0; kk < 16; ++kk) {
        f32x4 av0 = *(const f32x4*)(ap + kk * 32);
        f32x4 av1 = *(const f32x4*)(ap + kk * 32 + 4);
        short8 a8;
        a8[0] = (short)f2bf(av0[0]); a8[1] = (short)f2bf(av0[1]);
        a8[2] = (short)f2bf(av0[2]); a8[3] = (short)f2bf(av0[3]);
        a8[4] = (short)f2bf(av1[0]); a8[5] = (short)f2bf(av1[1]);
        a8[6] = (short)f2bf(av1[2]); a8[7] = (short)f2bf(av1[3]);
#pragma unroll
        for (int t = 0; t < 16; ++t) {
            short8 b8 = *(const short8*)(Wxb_t +
                        (size_t)(n0 + t * 16 + m) * D_ + kk * 32 + q * 8);
            acc[t] = __builtin_amdgcn_mfma_f32_16x16x32_bf16(a8, b8, acc[t], 0, 0, 0);
        }
    }

#pragma unroll
    for (int t = 0; t < 16; ++t) {
        int n = n0 + t * 16 + m;            // C/D: col = lane&15
        float bias = bxh[n];
        u16x4 o;
#pragma unroll
        for (int r = 0; r < 4; ++r) o[r] = f2bf(acc[t][r] + bias);
        // rows q*4+r -> b = brow + q*4 + r (consecutive) -> 8B store
        *(u16x4*)(xpT + ((size_t)l * H_ + n) * B_ + brow + q * 4) = o;
    }
}

// ------------------------------------------------------------- k2: scan
// Grid: 256 WGs x 128 thr. group g=blk&7 (rows g*16..+15), wgi=blk>>3
// (cols wgi*32..+31; wave w owns 16). Wh slice resident in VGPRs.
__global__ __launch_bounds__(128, 1) void k2_scan(
    const unsigned short* __restrict__ Whb_t,
    const unsigned short* __restrict__ xpT,
    unsigned short* __restrict__ hs,
    int* __restrict__ bar)
{
    const int g    = blockIdx.x & 7;
    const int wgi  = blockIdx.x >> 3;
    const int tid  = threadIdx.x;
    const int w    = tid >> 6;
    const int lane = tid & 63;
    const int m    = lane & 15, q = lane >> 4;
    const int b0   = g * 16;
    const int col  = wgi * 32 + w * 16 + m;   // B-frag col AND C/D col

    // persistent B fragments: Wh[k][col], k = kk*32 + q*8 + j
    short8 bfrag[32];
    {
        const unsigned short* wp = Whb_t + (size_t)col * H_ + q * 8;
#pragma unroll
        for (int kk = 0; kk < 32; ++kk)
            bfrag[kk] = *(const short8*)(wp + kk * 32);
    }

    float c[4] = {0.f, 0.f, 0.f, 0.f};
    int* cnt = bar + g * 32;        // 128B-separated per group
    int* gen = bar + g * 32 + 16;

    for (int l = 0; l < L_; ++l) {
        f32x4 acc0 = {0.f,0.f,0.f,0.f}, acc1 = {0.f,0.f,0.f,0.f};
        f32x4 acc2 = {0.f,0.f,0.f,0.f}, acc3 = {0.f,0.f,0.f,0.f};
        if (l > 0) {
            const unsigned short* ap =
                hs + ((size_t)(l - 1) * B_ + b0 + m) * H_ + q * 8;
#pragma unroll
            for (int kk = 0; kk < 32; kk += 4) {
                short8 a0 = *(const short8*)(ap + (kk + 0) * 32);
                short8 a1 = *(const short8*)(ap + (kk + 1) * 32);
                short8 a2 = *(const short8*)(ap + (kk + 2) * 32);
                short8 a3 = *(const short8*)(ap + (kk + 3) * 32);
                acc0 = __builtin_amdgcn_mfma_f32_16x16x32_bf16(a0, bfrag[kk + 0], acc0, 0, 0, 0);
                acc1 = __builtin_amdgcn_mfma_f32_16x16x32_bf16(a1, bfrag[kk + 1], acc1, 0, 0, 0);
                acc2 = __builtin_amdgcn_mfma_f32_16x16x32_bf16(a2, bfrag[kk + 2], acc2, 0, 0, 0);
                acc3 = __builtin_amdgcn_mfma_f32_16x16x32_bf16(a3, bfrag[kk + 3], acc3, 0, 0, 0);
            }
        }
        // z rows (b = b0+q*4+r) at fixed col; xpT is [l][n][b] so 4 b's are contiguous
        u16x4 xv = *(const u16x4*)(xpT + ((size_t)l * H_ + col) * B_ + b0 + q * 4);
        unsigned short ho[4];
#pragma unroll
        for (int r = 0; r < 4; ++r) {
            float z  = acc0[r] + acc1[r] + acc2[r] + acc3[r] + bf2f(xv[r]);
            float e  = __expf(-z);
            float sg = 1.f / (1.f + e);           // sigmoid(z)
            float gg = 2.f / (1.f + e * e) - 1.f; // tanh(z) via same exp
            c[r] = sg * (c[r] + gg);
            float ec = __expf(-2.f * c[r]);
            float th = 2.f / (1.f + ec) - 1.f;    // tanh(c)
            ho[r] = f2bf(sg * th);
        }
        unsigned short* hp = hs + ((size_t)l * B_ + b0 + q * 4) * H_ + col;
        hp[0] = ho[0]; hp[H_] = ho[1]; hp[2 * H_] = ho[2]; hp[3 * H_] = ho[3];

        // ---- per-group barrier (32 WGs), agent scope, sense via generation
        __syncthreads();
        if (tid == 0) {
            __threadfence();  // release: publish h stores device-wide
            int gcur = __hip_atomic_load(gen, __ATOMIC_RELAXED, __HIP_MEMORY_SCOPE_AGENT);
            int arr  = __hip_atomic_fetch_add(cnt, 1, __ATOMIC_ACQ_REL, __HIP_MEMORY_SCOPE_AGENT);
            if (arr == 31) {
                __hip_atomic_store(cnt, 0, __ATOMIC_RELAXED, __HIP_MEMORY_SCOPE_AGENT);
                __hip_atomic_fetch_add(gen, 1, __ATOMIC_RELEASE, __HIP_MEMORY_SCOPE_AGENT);
            } else {
                while (__hip_atomic_load(gen, __ATOMIC_ACQUIRE, __HIP_MEMORY_SCOPE_AGENT) == gcur)
                    __builtin_amdgcn_s_sleep(1);
            }
            __threadfence();  // acquire: invalidate stale cached h
        }
        __syncthreads();
    }
}

// ------------------------------------------------------------- k3: output
// One wave per (b,l) row: u = hs[l][b]@Wo, shuffle-reduce, sigmoid + mask.
__global__ __launch_bounds__(256) void k3_out(
    const unsigned short* __restrict__ hs,
    const float* __restrict__ Wo, const float* __restrict__ bo,
    const int* __restrict__ slen, float* __restrict__ out)
{
    const int w    = threadIdx.x >> 6;
    const int lane = threadIdx.x & 63;
    const int r    = blockIdx.x * 4 + w;   // r = b*L + l
    const int b    = r >> 8;
    const int l    = r & 255;

    const unsigned short* hp = hs + ((size_t)l * B_ + b) * H_ + lane * 16;
    const float* wp = Wo + (size_t)lane * 32;   // Wo[k][o], k = lane*16+j
    float u0 = 0.f, u1 = 0.f;
#pragma unroll
    for (int j0 = 0; j0 < 16; j0 += 8) {
        short8 hv = *(const short8*)(hp + j0);
#pragma unroll
        for (int j = 0; j < 8; ++j) {
            float h = bf2f((unsigned short)hv[j]);
            f32x2 wv = *(const f32x2*)(wp + (j0 + j) * 2);
            u0 += h * wv[0];
            u1 += h * wv[1];
        }
    }
#pragma unroll
    for (int off = 32; off; off >>= 1) {
        u0 += __shfl_down(u0, off);
        u1 += __shfl_down(u1, off);
    }
    if (lane == 0) {
        float o0, o1;
        if (l <= slen[b]) {
            o0 = 1.f / (1.f + __expf(-(u0 + bo[0])));
            o1 = 1.f / (1.f + __expf(-(u1 + bo[1])));
        } else {
            o0 = 0.f; o1 = 1.f;
        }
        out[(size_t)r * 2]     = o0;
        out[(size_t)r * 2 + 1] = o1;
    }
}

// ----------------------------------------------------------------- launch
extern "C" void kernel_launch(void* const* d_in, const int* in_sizes, int n_in,
                              void* d_out, int out_size, void* d_ws, size_t ws_size,
                              hipStream_t stream)
{
    const float* x    = (const float*)d_in[0];
    const int*   slen = (const int*)d_in[1];
    const float* Wh   = (const float*)d_in[2];
    const float* bh   = (const float*)d_in[3];
    const float* Wx   = (const float*)d_in[4];
    const float* bx   = (const float*)d_in[5];
    const float* Wo   = (const float*)d_in[6];
    const float* bo   = (const float*)d_in[7];
    float* out = (float*)d_out;

    char* ws = (char*)d_ws;
    unsigned short* Whb_t = (unsigned short*)(ws);                     // 2 MiB
    unsigned short* Wxb_t = (unsigned short*)(ws + (2u << 20));        // 1 MiB
    float*          bxh   = (float*)(ws + (3u << 20));                 // 4 KiB
    int*            bar   = (int*)(ws + (3u << 20) + 4096);            // 1 KiB
    unsigned short* xpT   = (unsigned short*)(ws + (4u << 20));        // 64 MiB
    unsigned short* hs    = (unsigned short*)(ws + (68u << 20));       // 64 MiB

    k0_prep<<<512, 256, 0, stream>>>(Wh, Wx, bh, bx, Whb_t, Wxb_t, bxh, bar);
    k1_xproj<<<2048, 256, 0, stream>>>(x, Wxb_t, bxh, xpT);
    k2_scan<<<256, 128, 0, stream>>>(Whb_t, xpT, hs, bar);
    k3_out<<<8192, 256, 0, stream>>>(hs, Wo, bo, slen, out);
}

// Round 2
// 2421.878 us; speedup vs baseline: 3.1476x; 3.1476x over previous
//
#include <hip/hip_runtime.h>

// RNNModule: LSTM-like scan with shared gate pre-activation.
// B=128, L=256, D=512, H=1024, O=2.
//
//  k0_prep : transpose+convert Wh/Wx to bf16 col-major, bxh=bx+bh, zero flags.
//  k1_xproj: xpT[l][n][b] = bf16( x[b,l,:]@Wx[:,n] + bx[n] + bh[n] )  (MFMA)
//  k2_scan : 256 sequential steps, 8 independent groups (16 batch rows each),
//            32 WGs/group. Wh slice VGPR-resident. Cross-WG h exchange goes
//            through agent-scope (sc1) atomics -> coherence point, so NO
//            __threadfence (no buffer_wbl2/buffer_inv L2 maintenance!).
//            Barrier = per-WG monotone flag + all-lane parallel poll.
//  k3_out  : out[b*L+l] = mask ? sigmoid(hs[l][b]@Wo + bo) : (0,1)

#define B_ 128
#define L_ 256
#define D_ 512
#define H_ 1024

typedef __attribute__((ext_vector_type(8))) short short8;
typedef __attribute__((ext_vector_type(4))) float f32x4;
typedef __attribute__((ext_vector_type(2))) float f32x2;
typedef __attribute__((ext_vector_type(4))) unsigned short u16x4;

__device__ __forceinline__ unsigned short f2bf(float f) {
    unsigned int u = __float_as_uint(f);
    return (unsigned short)((u + 0x8000u) >> 16);  // round-half-up to bf16
}
__device__ __forceinline__ float bf2f(unsigned short s) {
    return __uint_as_float(((unsigned int)s) << 16);
}

// 16B A-fragment load via two 64-bit agent-scope (sc1) atomic loads:
// bypasses (possibly stale) L1/L2, reads the coherence point directly.
__device__ __forceinline__ short8 ld_frag_coherent(const unsigned short* p) {
    union { unsigned long long u[2]; short8 s; } v;
    v.u[0] = __hip_atomic_load((const unsigned long long*)p,
                               __ATOMIC_RELAXED, __HIP_MEMORY_SCOPE_AGENT);
    v.u[1] = __hip_atomic_load((const unsigned long long*)(p + 4),
                               __ATOMIC_RELAXED, __HIP_MEMORY_SCOPE_AGENT);
    return v.s;
}

// ---------------------------------------------------------------- k0: prep
__global__ __launch_bounds__(256) void k0_prep(
    const float* __restrict__ Wh, const float* __restrict__ Wx,
    const float* __restrict__ bh, const float* __restrict__ bx,
    unsigned short* __restrict__ Whb_t, unsigned short* __restrict__ Wxb_t,
    float* __restrict__ bxh, int* __restrict__ bar)
{
    const int stride = gridDim.x * blockDim.x;
    const int t0 = blockIdx.x * blockDim.x + threadIdx.x;
    for (int i = t0; i < H_ * H_; i += stride) {
        int n = i >> 10, k = i & 1023;
        Whb_t[i] = f2bf(Wh[k * H_ + n]);
    }
    for (int i = t0; i < H_ * D_; i += stride) {
        int n = i >> 9, k = i & 511;
        Wxb_t[i] = f2bf(Wx[k * H_ + n]);
    }
    for (int i = t0; i < H_; i += stride) bxh[i] = bx[i] + bh[i];
    for (int i = t0; i < 8 * 512; i += stride) bar[i] = 0;   // 8 groups x 32 flags x 64B
}

// ------------------------------------------------------------ k1: x @ Wx
__global__ __launch_bounds__(256) void k1_xproj(
    const float* __restrict__ x, const unsigned short* __restrict__ Wxb_t,
    const float* __restrict__ bxh, unsigned short* __restrict__ xpT)
{
    const int nt   = blockIdx.x & 3;
    const int mt   = blockIdx.x >> 2;
    const int w    = threadIdx.x >> 6;
    const int lane = threadIdx.x & 63;
    const int m    = lane & 15, q = lane >> 4;
    const int m0   = mt * 64;
    const int l    = m0 >> 7;
    const int brow = (m0 & 127) + w * 16;
    const int n0   = nt * 256;

    const float* ap = x + ((size_t)(brow + m) * L_ + l) * D_ + q * 8;

    f32x4 acc[16];
#pragma unroll
    for (int t = 0; t < 16; ++t) acc[t] = (f32x4){0.f, 0.f, 0.f, 0.f};

#pragma unroll 4
    for (int kk = 0; kk < 16; ++kk) {
        f32x4 av0 = *(const f32x4*)(ap + kk * 32);
        f32x4 av1 = *(const f32x4*)(ap + kk * 32 + 4);
        short8 a8;
        a8[0] = (short)f2bf(av0[0]); a8[1] = (short)f2bf(av0[1]);
        a8[2] = (short)f2bf(av0[2]); a8[3] = (short)f2bf(av0[3]);
        a8[4] = (short)f2bf(av1[0]); a8[5] = (short)f2bf(av1[1]);
        a8[6] = (short)f2bf(av1[2]); a8[7] = (short)f2bf(av1[3]);
#pragma unroll
        for (int t = 0; t < 16; ++t) {
            short8 b8 = *(const short8*)(Wxb_t +
                        (size_t)(n0 + t * 16 + m) * D_ + kk * 32 + q * 8);
            acc[t] = __builtin_amdgcn_mfma_f32_16x16x32_bf16(a8, b8, acc[t], 0, 0, 0);
        }
    }

#pragma unroll
    for (int t = 0; t < 16; ++t) {
        int n = n0 + t * 16 + m;
        float bias = bxh[n];
        u16x4 o;
#pragma unroll
        for (int r = 0; r < 4; ++r) o[r] = f2bf(acc[t][r] + bias);
        *(u16x4*)(xpT + ((size_t)l * H_ + n) * B_ + brow + q * 4) = o;
    }
}

// ------------------------------------------------------------- k2: scan
// Grid: 256 WGs x 128 thr. group g=blk&7 (rows g*16..+15; also the likely
// XCD under round-robin dispatch -> locality heuristic only), wgi=blk>>3
// (cols wgi*32..+31; wave w owns 16). Wh slice resident in VGPRs.
__global__ __launch_bounds__(128, 1) void k2_scan(
    const unsigned short* __restrict__ Whb_t,
    const unsigned short* __restrict__ xpT,
    unsigned short* __restrict__ hs,
    int* __restrict__ bar)
{
    const int g    = blockIdx.x & 7;
    const int wgi  = blockIdx.x >> 3;
    const int tid  = threadIdx.x;
    const int w    = tid >> 6;
    const int lane = tid & 63;
    const int m    = lane & 15, q = lane >> 4;
    const int b0   = g * 16;
    const int col  = wgi * 32 + w * 16 + m;   // B-frag col AND C/D col

    // persistent B fragments: Wh[k][col], k = kk*32 + q*8 + j
    short8 bfrag[32];
    {
        const unsigned short* wp = Whb_t + (size_t)col * H_ + q * 8;
#pragma unroll
        for (int kk = 0; kk < 32; ++kk)
            bfrag[kk] = *(const short8*)(wp + kk * 32);
    }

    float c[4] = {0.f, 0.f, 0.f, 0.f};
    int* flags  = bar + g * 512;          // 32 flags, 64B apart
    int* myflag = flags + wgi * 16;

    for (int l = 0; l < L_; ++l) {
        // xpT is independent of the recurrence: issue early
        u16x4 xv = *(const u16x4*)(xpT + ((size_t)l * H_ + col) * B_ + b0 + q * 4);

        f32x4 acc0 = {0.f,0.f,0.f,0.f}, acc1 = {0.f,0.f,0.f,0.f};
        f32x4 acc2 = {0.f,0.f,0.f,0.f}, acc3 = {0.f,0.f,0.f,0.f};
        if (l > 0) {
            const unsigned short* ap =
                hs + ((size_t)(l - 1) * B_ + b0 + m) * H_ + q * 8;
#pragma unroll
            for (int kk = 0; kk < 32; kk += 4) {
                short8 a0 = ld_frag_coherent(ap + (kk + 0) * 32);
                short8 a1 = ld_frag_coherent(ap + (kk + 1) * 32);
                short8 a2 = ld_frag_coherent(ap + (kk + 2) * 32);
                short8 a3 = ld_frag_coherent(ap + (kk + 3) * 32);
                acc0 = __builtin_amdgcn_mfma_f32_16x16x32_bf16(a0, bfrag[kk + 0], acc0, 0, 0, 0);
                acc1 = __builtin_amdgcn_mfma_f32_16x16x32_bf16(a1, bfrag[kk + 1], acc1, 0, 0, 0);
                acc2 = __builtin_amdgcn_mfma_f32_16x16x32_bf16(a2, bfrag[kk + 2], acc2, 0, 0, 0);
                acc3 = __builtin_amdgcn_mfma_f32_16x16x32_bf16(a3, bfrag[kk + 3], acc3, 0, 0, 0);
            }
        }
        unsigned short ho[4];
#pragma unroll
        for (int r = 0; r < 4; ++r) {
            float z  = acc0[r] + acc1[r] + acc2[r] + acc3[r] + bf2f(xv[r]);
            float e  = __expf(-z);
            float sg = 1.f / (1.f + e);           // sigmoid(z)
            float gg = 2.f / (1.f + e * e) - 1.f; // tanh(z) via same exp
            c[r] = sg * (c[r] + gg);
            float ec = __expf(-2.f * c[r]);
            float th = 2.f / (1.f + ec) - 1.f;    // tanh(c)
            ho[r] = f2bf(sg * th);
        }
        // h stores: agent-scope (sc1) -> land at coherence point, no wbl2 needed
        unsigned short* hp = hs + ((size_t)l * B_ + b0 + q * 4) * H_ + col;
#pragma unroll
        for (int r = 0; r < 4; ++r)
            __hip_atomic_store(hp + r * H_, ho[r],
                               __ATOMIC_RELAXED, __HIP_MEMORY_SCOPE_AGENT);

        // __syncthreads drains vmcnt(0) for BOTH waves before the flag goes up
        __syncthreads();
        if (tid == 0)
            __hip_atomic_store(myflag, l + 1,
                               __ATOMIC_RELAXED, __HIP_MEMORY_SCOPE_AGENT);
        // all-lane parallel poll: lane i (i<32) watches flag i (monotone, no reset)
        const int want = l + 1;
        while (true) {
            bool mine = true;
            if (lane < 32)
                mine = __hip_atomic_load(flags + lane * 16,
                         __ATOMIC_RELAXED, __HIP_MEMORY_SCOPE_AGENT) >= want;
            if (__all(mine)) break;
            __builtin_amdgcn_s_sleep(2);
        }
        asm volatile("" ::: "memory");   // compiler barrier: no hoisting across the spin
    }
}

// ------------------------------------------------------------- k3: output
__global__ __launch_bounds__(256) void k3_out(
    const unsigned short* __restrict__ hs,
    const float* __restrict__ Wo, const float* __restrict__ bo,
    const int* __restrict__ slen, float* __restrict__ out)
{
    const int w    = threadIdx.x >> 6;
    const int lane = threadIdx.x & 63;
    const int r    = blockIdx.x * 4 + w;   // r = b*L + l
    const int b    = r >> 8;
    const int l    = r & 255;

    const unsigned short* hp = hs + ((size_t)l * B_ + b) * H_ + lane * 16;
    const float* wp = Wo + (size_t)lane * 32;
    float u0 = 0.f, u1 = 0.f;
#pragma unroll
    for (int j0 = 0; j0 < 16; j0 += 8) {
        short8 hv = *(const short8*)(hp + j0);
#pragma unroll
        for (int j = 0; j < 8; ++j) {
            float h = bf2f((unsigned short)hv[j]);
            f32x2 wv = *(const f32x2*)(wp + (j0 + j) * 2);
            u0 += h * wv[0];
            u1 += h * wv[1];
        }
    }
#pragma unroll
    for (int off = 32; off; off >>= 1) {
        u0 += __shfl_down(u0, off);
        u1 += __shfl_down(u1, off);
    }
    if (lane == 0) {
        float o0, o1;
        if (l <= slen[b]) {
            o0 = 1.f / (1.f + __expf(-(u0 + bo[0])));
            o1 = 1.f / (1.f + __expf(-(u1 + bo[1])));
        } else {
            o0 = 0.f; o1 = 1.f;
        }
        out[(size_t)r * 2]     = o0;
        out[(size_t)r * 2 + 1] = o1;
    }
}

// ----------------------------------------------------------------- launch
extern "C" void kernel_launch(void* const* d_in, const int* in_sizes, int n_in,
                              void* d_out, int out_size, void* d_ws, size_t ws_size,
                              hipStream_t stream)
{
    const float* x    = (const float*)d_in[0];
    const int*   slen = (const int*)d_in[1];
    const float* Wh   = (const float*)d_in[2];
    const float* bh   = (const float*)d_in[3];
    const float* Wx   = (const float*)d_in[4];
    const float* bx   = (const float*)d_in[5];
    const float* Wo   = (const float*)d_in[6];
    const float* bo   = (const float*)d_in[7];
    float* out = (float*)d_out;

    char* ws = (char*)d_ws;
    unsigned short* Whb_t = (unsigned short*)(ws);                     // 2 MiB
    unsigned short* Wxb_t = (unsigned short*)(ws + (2u << 20));        // 1 MiB
    float*          bxh   = (float*)(ws + (3u << 20));                 // 4 KiB
    int*            bar   = (int*)(ws + (3u << 20) + 4096);            // 16 KiB
    unsigned short* xpT   = (unsigned short*)(ws + (4u << 20));        // 64 MiB
    unsigned short* hs    = (unsigned short*)(ws + (68u << 20));       // 64 MiB

    k0_prep<<<512, 256, 0, stream>>>(Wh, Wx, bh, bx, Whb_t, Wxb_t, bxh, bar);
    k1_xproj<<<2048, 256, 0, stream>>>(x, Wxb_t, bxh, xpT);
    k2_scan<<<256, 128, 0, stream>>>(Whb_t, xpT, hs, bar);
    k3_out<<<8192, 256, 0, stream>>>(hs, Wo, bo, slen, out);
}